// Round 1
// 513.430 us; speedup vs baseline: 1.0453x; 1.0453x over previous
//
#include <hip/hip_runtime.h>

// ExplodedLogit: out (512, 1 + 512*512) fp32.
//   scores = x @ W.T + b            (512,)
//   idx    = argmax(scores)
//   out[i][0]             = scores[i]
//   out[i][1 + r*512 + j] = scores[i] * (j==idx ? MASK_VAL : 1.0f)
//
// R4: memset-shaped flat fill. Timed graph = harness poison (343 us, fixed)
// + our kernels (~193 us). Old fill ran ~2.9 TB/s vs memset's reported 6.25.
// New fill: whole 537 MB output is exactly 33,554,560 float4s (base aligned),
// so cover it flat — no per-row chunks, no scalar head/tail, col-0 included.
// Row/offset from flat index via 262145 = 2^18+1 division identity.
// 32768 blocks x 256 thr x 4 stores: tiny short-lived blocks like the rocclr
// memset, but capped wg count so CP dispatch rate can't become the bound.

#define TRACKS 512
#define FEATURES 256
#define ROWSTRIDE 262145            // 1 + 512*512
#define MASK_VAL (-105.918914f)     // float32(log(1e-46))

#define TOTAL_F4 33554560u          // 512*262145/4 (exact)
#define FILL_BLOCKS 32768
#define FILL_TPB 256

typedef float vf4 __attribute__((ext_vector_type(4)));

// ---- kernel 1: one wave per row dot-product ----
__global__ __launch_bounds__(64) void scores_kernel(
    const float* __restrict__ x, const float* __restrict__ W,
    const float* __restrict__ b, float* __restrict__ scores) {
  int row = blockIdx.x;
  int lane = threadIdx.x;  // 0..63
  const float4* xr = (const float4*)(x + row * FEATURES);
  const float4* wr = (const float4*)W;
  float4 xv = xr[lane];
  float4 wv = wr[lane];
  float s = xv.x * wv.x + xv.y * wv.y + xv.z * wv.z + xv.w * wv.w;
#pragma unroll
  for (int off = 32; off; off >>= 1) s += __shfl_down(s, off);
  if (lane == 0) scores[row] = s + b[0];
}

// ---- kernel 2: argmax (first-index tie-break) ----
__global__ __launch_bounds__(512) void argmax_kernel(
    const float* __restrict__ scores, int* __restrict__ idx_out) {
  __shared__ float svals[TRACKS];
  __shared__ int sidx[TRACKS];
  int t = threadIdx.x;
  float v = scores[t];
  svals[t] = v;
  sidx[t] = t;
  __syncthreads();
  for (int off = 256; off; off >>= 1) {
    if (t < off) {
      float v2 = svals[t + off];
      int i2 = sidx[t + off];
      if (v2 > svals[t] || (v2 == svals[t] && i2 < sidx[t])) {
        svals[t] = v2;
        sidx[t] = i2;
      }
    }
    __syncthreads();
  }
  if (t == 0) idx_out[0] = sidx[0];
}

// ---- kernel 3: flat memset-shaped stream-out of the whole 537 MB ----
// p = flat float index (< 2^28, fits u32). row = p / 262145 via
// q = p >> 18;  rem = p - q*(2^18+1) = p - (q<<18) - q;  if (rem<0) row=q-1.
// rem == 0        -> column 0  -> scores[row]
// rem >= 1        -> bulk j = (rem-1) & 511 -> scores[row] * (j==idx ? M : 1)
__global__ __launch_bounds__(FILL_TPB) void fill_flat(
    const float* __restrict__ scores, const int* __restrict__ idxp,
    float* __restrict__ out) {
  unsigned g = blockIdx.x * FILL_TPB + threadIdx.x;
  int idx = *idxp;
  vf4* outv = (vf4*)out;
  for (; g < TOTAL_F4; g += (unsigned)FILL_BLOCKS * FILL_TPB) {
    unsigned p = g << 2;  // flat float index of component 0
    unsigned q = p >> 18;
    int rem = (int)p - (int)((q << 18) + q);
    int row = (int)q;
    if (rem < 0) { row -= 1; rem += ROWSTRIDE; }
    float s = scores[row];
    float sm = s * MASK_VAL;
    vf4 val;
    {
      float v = (((rem - 1) & 511) == idx) ? sm : s;
      val.x = (rem == 0) ? s : v;
    }
    rem++;
    if (rem == ROWSTRIDE) { rem = 0; row++; s = scores[row]; sm = s * MASK_VAL; }
    {
      float v = (((rem - 1) & 511) == idx) ? sm : s;
      val.y = (rem == 0) ? s : v;
    }
    rem++;
    if (rem == ROWSTRIDE) { rem = 0; row++; s = scores[row]; sm = s * MASK_VAL; }
    {
      float v = (((rem - 1) & 511) == idx) ? sm : s;
      val.z = (rem == 0) ? s : v;
    }
    rem++;
    if (rem == ROWSTRIDE) { rem = 0; row++; s = scores[row]; sm = s * MASK_VAL; }
    {
      float v = (((rem - 1) & 511) == idx) ? sm : s;
      val.w = (rem == 0) ? s : v;
    }
    outv[g] = val;
  }
}

extern "C" void kernel_launch(void* const* d_in, const int* in_sizes, int n_in,
                              void* d_out, int out_size, void* d_ws,
                              size_t ws_size, hipStream_t stream) {
  const float* x = (const float*)d_in[0];
  const float* W = (const float*)d_in[1];
  const float* b = (const float*)d_in[2];
  float* out = (float*)d_out;

  float* scores = (float*)d_ws;              // 512 floats
  int* idx = (int*)((float*)d_ws + TRACKS);  // 1 int

  scores_kernel<<<TRACKS, 64, 0, stream>>>(x, W, b, scores);
  argmax_kernel<<<1, TRACKS, 0, stream>>>(scores, idx);
  fill_flat<<<FILL_BLOCKS, FILL_TPB, 0, stream>>>(scores, idx, out);
}